// Round 4
// baseline (1145.658 us; speedup 1.0000x reference)
//
#include <hip/hip_runtime.h>
#include <hip/hip_bf16.h>

#define NORM_EPS_F 1e-6f
#define COS_EPS_F  1e-8f
#define BK   512       // vertices per bucket (512 -> 1954 blocks at N=1M: ~2x occupancy vs 1024)
#define BKSH 9
#define NBGMAX 2048    // max buckets per pass (hist LDS = 8 KB)

__device__ __forceinline__ void atomAddF(float* p, float v) {
    unsafeAtomicAdd(p, v);   // hardware global_atomic_add_f32
}

// Block-wide reduce of NV floats -> NV global atomics. All 256 threads must call.
template<int NV>
__device__ __forceinline__ void blockReduceAtomicN(float (&v)[NV], float* dst) {
    #pragma unroll
    for (int off = 32; off > 0; off >>= 1) {
        #pragma unroll
        for (int k = 0; k < NV; ++k) v[k] += __shfl_down(v[k], off, 64);
    }
    __shared__ float red[4][NV];
    int wave = threadIdx.x >> 6, lane = threadIdx.x & 63;
    if (lane == 0) {
        #pragma unroll
        for (int k = 0; k < NV; ++k) red[wave][k] = v[k];
    }
    __syncthreads();
    if (threadIdx.x == 0) {
        float s[NV];
        #pragma unroll
        for (int k = 0; k < NV; ++k) s[k] = 0.f;
        for (int w = 0; w < 4; ++w)
            #pragma unroll
            for (int k = 0; k < NV; ++k) s[k] += red[w][k];
        #pragma unroll
        for (int k = 0; k < NV; ++k) atomAddF(&dst[k], s[k]);
    }
}

// ======================= FAST PATH =======================

// Pack V into 32B/vertex {rec.xyz,0, gt.xyz,0}; fold L1 term.
__global__ void __launch_bounds__(256) pack_l1_kernel(
    const float* __restrict__ Vr, const float* __restrict__ Vg,
    float4* __restrict__ Vp, float* __restrict__ accum, int N)
{
    int i = blockIdx.x * blockDim.x + threadIdx.x;
    float l1[1] = {0.f};
    if (i < N) {
        float rx = Vr[3 * i], ry = Vr[3 * i + 1], rz = Vr[3 * i + 2];
        float gx = Vg[3 * i], gy = Vg[3 * i + 1], gz = Vg[3 * i + 2];
        Vp[2 * i]     = make_float4(rx, ry, rz, 0.f);
        Vp[2 * i + 1] = make_float4(gx, gy, gz, 0.f);
        l1[0] = fabsf(rx - gx) + fabsf(ry - gy) + fabsf(rz - gz);
    }
    blockReduceAtomicN<1>(l1, &accum[0]);
}

// Face normals for both meshes -> packed {nr, ng} float4 pairs.
// 2 faces per thread (f and f+half) -> 12 gather loads in flight per lane.
__global__ void __launch_bounds__(256) fn_kernel(
    const float4* __restrict__ Vp, const int* __restrict__ faces,
    float4* __restrict__ FN, int F)
{
    int half = (F + 1) >> 1;
    int t = blockIdx.x * blockDim.x + threadIdx.x;
    if (t >= half) return;
    int fi[2] = {t, t + half};
    int n = (fi[1] < F) ? 2 : 1;
    int idx[2][3];
    #pragma unroll
    for (int k = 0; k < 2; ++k) {
        if (k < n) {
            idx[k][0] = faces[3 * fi[k]];
            idx[k][1] = faces[3 * fi[k] + 1];
            idx[k][2] = faces[3 * fi[k] + 2];
        }
    }
    float4 r0[2], r1[2], r2[2], g0[2], g1[2], g2[2];
    #pragma unroll
    for (int k = 0; k < 2; ++k) {
        if (k < n) {
            r0[k] = Vp[2 * idx[k][0]]; g0[k] = Vp[2 * idx[k][0] + 1];
            r1[k] = Vp[2 * idx[k][1]]; g1[k] = Vp[2 * idx[k][1] + 1];
            r2[k] = Vp[2 * idx[k][2]]; g2[k] = Vp[2 * idx[k][2] + 1];
        }
    }
    #pragma unroll
    for (int k = 0; k < 2; ++k) {
        if (k < n) {
            float ax = r1[k].x - r0[k].x, ay = r1[k].y - r0[k].y, az = r1[k].z - r0[k].z;
            float bx = r2[k].x - r0[k].x, by = r2[k].y - r0[k].y, bz = r2[k].z - r0[k].z;
            FN[2 * fi[k]] = make_float4(ay * bz - az * by, az * bx - ax * bz, ax * by - ay * bx, 0.f);
            ax = g1[k].x - g0[k].x; ay = g1[k].y - g0[k].y; az = g1[k].z - g0[k].z;
            bx = g2[k].x - g0[k].x; by = g2[k].y - g0[k].y; bz = g2[k].z - g0[k].z;
            FN[2 * fi[k] + 1] = make_float4(ay * bz - az * by, az * bx - ax * bz, ax * by - ay * bx, 0.f);
        }
    }
}

// Bucket face incidences for bucket range [b0, b0+bcnt). Record = (face<<BKSH)|lv.
__global__ void __launch_bounds__(256) bucket_faces_kernel(
    const int* __restrict__ faces, int* __restrict__ cnt,
    unsigned* __restrict__ recF, int capF, int F, int b0, int bcnt, int chunk)
{
    __shared__ int hist[NBGMAX];
    int f0 = blockIdx.x * chunk;
    int f1 = min(f0 + chunk, F);
    for (int b = threadIdx.x; b < bcnt; b += blockDim.x) hist[b] = 0;
    __syncthreads();
    for (int f = f0 + threadIdx.x; f < f1; f += blockDim.x) {
        #pragma unroll
        for (int c = 0; c < 3; ++c) {
            unsigned bb = ((unsigned)faces[3 * f + c] >> BKSH) - (unsigned)b0;
            if (bb < (unsigned)bcnt) atomicAdd(&hist[bb], 1);
        }
    }
    __syncthreads();
    for (int b = threadIdx.x; b < bcnt; b += blockDim.x) {
        int h = hist[b];
        if (h) hist[b] = atomicAdd(&cnt[b], h);   // reserve [base, base+h)
    }
    __syncthreads();
    for (int f = f0 + threadIdx.x; f < f1; f += blockDim.x) {
        #pragma unroll
        for (int c = 0; c < 3; ++c) {
            int vtx = faces[3 * f + c];
            unsigned bb = ((unsigned)vtx >> BKSH) - (unsigned)b0;
            if (bb < (unsigned)bcnt) {
                int pos = atomicAdd(&hist[bb], 1);
                if (pos < capF)
                    recF[(size_t)bb * capF + pos] =
                        ((unsigned)f << BKSH) | (unsigned)(vtx & (BK - 1));
            }
        }
    }
}

// One block per bucket: LDS-accumulate vertex normals (unroll-4 batched gathers),
// then normal-cos loss. use_fn: read precomputed FN; else recompute from faces.
__global__ void __launch_bounds__(256) accum_normals_kernel(
    const float4* __restrict__ Vp, const float4* __restrict__ FN,
    const int* __restrict__ faces,
    const int* __restrict__ cnt, const unsigned* __restrict__ recF, int capF,
    float* __restrict__ accum, int N, int b0, int use_fn)
{
    __shared__ float vnr[3 * BK];
    __shared__ float vng[3 * BK];
    int g = blockIdx.x;
    for (int i = threadIdx.x; i < 3 * BK; i += blockDim.x) { vnr[i] = 0.f; vng[i] = 0.f; }
    __syncthreads();

    const unsigned* rec = recF + (size_t)g * capF;
    int n = min(cnt[g], capF);
    int i = threadIdx.x;
    if (use_fn) {
        for (; i + 768 < n; i += 1024) {
            unsigned rc[4];
            rc[0] = rec[i]; rc[1] = rec[i + 256]; rc[2] = rec[i + 512]; rc[3] = rec[i + 768];
            float4 nr[4], ng[4];
            #pragma unroll
            for (int k = 0; k < 4; ++k) {
                int f = rc[k] >> BKSH;
                nr[k] = FN[2 * f];
                ng[k] = FN[2 * f + 1];
            }
            #pragma unroll
            for (int k = 0; k < 4; ++k) {
                int lv = rc[k] & (BK - 1);
                atomicAdd(&vnr[3 * lv + 0], nr[k].x);
                atomicAdd(&vnr[3 * lv + 1], nr[k].y);
                atomicAdd(&vnr[3 * lv + 2], nr[k].z);
                atomicAdd(&vng[3 * lv + 0], ng[k].x);
                atomicAdd(&vng[3 * lv + 1], ng[k].y);
                atomicAdd(&vng[3 * lv + 2], ng[k].z);
            }
        }
    }
    for (; i < n; i += 256) {
        unsigned rc = rec[i];
        int lv = rc & (BK - 1);
        int f  = rc >> BKSH;
        float4 nr, ng;
        if (use_fn) {
            nr = FN[2 * f];
            ng = FN[2 * f + 1];
        } else {
            int i0 = faces[3 * f], i1 = faces[3 * f + 1], i2 = faces[3 * f + 2];
            float4 r0 = Vp[2 * i0], r1 = Vp[2 * i1], r2 = Vp[2 * i2];
            float4 g0 = Vp[2 * i0 + 1], g1 = Vp[2 * i1 + 1], g2 = Vp[2 * i2 + 1];
            float ax = r1.x - r0.x, ay = r1.y - r0.y, az = r1.z - r0.z;
            float bx = r2.x - r0.x, by = r2.y - r0.y, bz = r2.z - r0.z;
            nr = make_float4(ay * bz - az * by, az * bx - ax * bz, ax * by - ay * bx, 0.f);
            ax = g1.x - g0.x; ay = g1.y - g0.y; az = g1.z - g0.z;
            bx = g2.x - g0.x; by = g2.y - g0.y; bz = g2.z - g0.z;
            ng = make_float4(ay * bz - az * by, az * bx - ax * bz, ax * by - ay * bx, 0.f);
        }
        atomicAdd(&vnr[3 * lv + 0], nr.x);
        atomicAdd(&vnr[3 * lv + 1], nr.y);
        atomicAdd(&vnr[3 * lv + 2], nr.z);
        atomicAdd(&vng[3 * lv + 0], ng.x);
        atomicAdd(&vng[3 * lv + 1], ng.y);
        atomicAdd(&vng[3 * lv + 2], ng.z);
    }
    __syncthreads();

    float ln[1] = {0.f};
    for (int lv = threadIdx.x; lv < BK; lv += blockDim.x) {
        int gv = ((b0 + g) << BKSH) + lv;
        if (gv < N) {
            float ax = vnr[3 * lv], ay = vnr[3 * lv + 1], az = vnr[3 * lv + 2];
            float bx = vng[3 * lv], by = vng[3 * lv + 1], bz = vng[3 * lv + 2];
            float na = sqrtf(ax * ax + ay * ay + az * az);
            float nb = sqrtf(bx * bx + by * by + bz * bz);
            float ia = 1.0f / fmaxf(na, NORM_EPS_F);
            float ib = 1.0f / fmaxf(nb, NORM_EPS_F);
            ax *= ia; ay *= ia; az *= ia;
            bx *= ib; by *= ib; bz *= ib;
            float dot = ax * bx + ay * by + az * bz;
            float nna = sqrtf(ax * ax + ay * ay + az * az);
            float nnb = sqrtf(bx * bx + by * by + bz * bz);
            float cosn = dot / (fmaxf(nna, COS_EPS_F) * fmaxf(nnb, COS_EPS_F));
            if (isnan(cosn)) cosn = 1.0f;
            ln[0] += 1.0f - cosn;
        }
    }
    blockReduceAtomicN<1>(ln, &accum[1]);
}

// Bucket Laplacian triplets by row bucket. Record = {(col<<BKSH)|lv, val}.
__global__ void __launch_bounds__(256) bucket_L_kernel(
    const int* __restrict__ rows, const int* __restrict__ cols,
    const float* __restrict__ vals, int* __restrict__ cnt,
    int2* __restrict__ recL, int capL, int nnz, int b0, int bcnt, int chunk)
{
    __shared__ int hist[NBGMAX];
    int i0 = blockIdx.x * chunk;
    int i1 = min(i0 + chunk, nnz);
    for (int b = threadIdx.x; b < bcnt; b += blockDim.x) hist[b] = 0;
    __syncthreads();
    for (int i = i0 + threadIdx.x; i < i1; i += blockDim.x) {
        unsigned bb = ((unsigned)rows[i] >> BKSH) - (unsigned)b0;
        if (bb < (unsigned)bcnt) atomicAdd(&hist[bb], 1);
    }
    __syncthreads();
    for (int b = threadIdx.x; b < bcnt; b += blockDim.x) {
        int h = hist[b];
        if (h) hist[b] = atomicAdd(&cnt[b], h);
    }
    __syncthreads();
    for (int i = i0 + threadIdx.x; i < i1; i += blockDim.x) {
        int r = rows[i];
        unsigned bb = ((unsigned)r >> BKSH) - (unsigned)b0;
        if (bb < (unsigned)bcnt) {
            int pos = atomicAdd(&hist[bb], 1);
            if (pos < capL)
                recL[(size_t)bb * capL + pos] = make_int2(
                    (int)(((unsigned)cols[i] << BKSH) | (unsigned)(r & (BK - 1))),
                    __float_as_int(vals[i]));
        }
    }
}

// One block per bucket: LDS-accumulate laplacian deltas (unroll-4 batched
// gathers: 8 float4 loads in flight), then lap-cos loss.
__global__ void __launch_bounds__(256) accum_lap_kernel(
    const float4* __restrict__ Vp,
    const int* __restrict__ cnt, const int2* __restrict__ recL, int capL,
    float* __restrict__ accum, int N, int b0)
{
    __shared__ float dlr[3 * BK];
    __shared__ float dlg[3 * BK];
    int g = blockIdx.x;
    for (int i = threadIdx.x; i < 3 * BK; i += blockDim.x) { dlr[i] = 0.f; dlg[i] = 0.f; }
    __syncthreads();

    const int2* rec = recL + (size_t)g * capL;
    int n = min(cnt[g], capL);
    int i = threadIdx.x;
    for (; i + 768 < n; i += 1024) {
        int2 rc[4];
        rc[0] = rec[i]; rc[1] = rec[i + 256]; rc[2] = rec[i + 512]; rc[3] = rec[i + 768];
        float4 pr[4], pg[4];
        #pragma unroll
        for (int k = 0; k < 4; ++k) {
            int col = (unsigned)rc[k].x >> BKSH;
            pr[k] = Vp[2 * col];
            pg[k] = Vp[2 * col + 1];
        }
        #pragma unroll
        for (int k = 0; k < 4; ++k) {
            int lv = (unsigned)rc[k].x & (BK - 1);
            float v = __int_as_float(rc[k].y);
            atomicAdd(&dlr[3 * lv + 0], v * pr[k].x);
            atomicAdd(&dlr[3 * lv + 1], v * pr[k].y);
            atomicAdd(&dlr[3 * lv + 2], v * pr[k].z);
            atomicAdd(&dlg[3 * lv + 0], v * pg[k].x);
            atomicAdd(&dlg[3 * lv + 1], v * pg[k].y);
            atomicAdd(&dlg[3 * lv + 2], v * pg[k].z);
        }
    }
    for (; i < n; i += 256) {
        int2 rc = rec[i];
        unsigned u = (unsigned)rc.x;
        int lv  = u & (BK - 1);
        int col = u >> BKSH;
        float v = __int_as_float(rc.y);
        float4 pr = Vp[2 * col];
        float4 pg = Vp[2 * col + 1];
        atomicAdd(&dlr[3 * lv + 0], v * pr.x);
        atomicAdd(&dlr[3 * lv + 1], v * pr.y);
        atomicAdd(&dlr[3 * lv + 2], v * pr.z);
        atomicAdd(&dlg[3 * lv + 0], v * pg.x);
        atomicAdd(&dlg[3 * lv + 1], v * pg.y);
        atomicAdd(&dlg[3 * lv + 2], v * pg.z);
    }
    __syncthreads();

    float vals2[2] = {0.f, 0.f};   // {lap loss, nonfinite count}
    for (int lv = threadIdx.x; lv < BK; lv += blockDim.x) {
        int gv = ((b0 + g) << BKSH) + lv;
        if (gv < N) {
            float px = dlr[3 * lv], py = dlr[3 * lv + 1], pz = dlr[3 * lv + 2];
            float qx = dlg[3 * lv], qy = dlg[3 * lv + 1], qz = dlg[3 * lv + 2];
            bool fin = isfinite(px) && isfinite(py) && isfinite(pz) &&
                       isfinite(qx) && isfinite(qy) && isfinite(qz);
            vals2[1] += fin ? 0.f : 1.f;
            float dotl = px * qx + py * qy + pz * qz;
            float npn = sqrtf(px * px + py * py + pz * pz);
            float nqn = sqrtf(qx * qx + qy * qy + qz * qz);
            float cosl = dotl / (fmaxf(npn, COS_EPS_F) * fmaxf(nqn, COS_EPS_F));
            if (isnan(cosl)) cosl = 1.0f;
            vals2[0] += 1.0f - cosl;
        }
    }
    blockReduceAtomicN<2>(vals2, &accum[2]);
}

__global__ void finalize_kernel(const float* __restrict__ accum,
                                float* __restrict__ out, int N)
{
    float invN = 1.0f / (float)N;
    float l1 = accum[0] * invN * (1.0f / 3.0f);
    float ln = accum[1] * invN;
    float ll = (accum[3] > 0.0f) ? 0.0f : accum[2] * invN;
    out[0] = 1.0f * l1 + 1.0f * ln + 0.1f * ll;
}

// ======================= FALLBACK PATH (round-1, known correct) =======================

__global__ void __launch_bounds__(256) face_normals_kernel(
    const float* __restrict__ Vr, const float* __restrict__ Vg,
    const int* __restrict__ faces,
    float* __restrict__ vn_rec, float* __restrict__ vn_gt, int F)
{
    int f = blockIdx.x * blockDim.x + threadIdx.x;
    if (f >= F) return;
    int i0 = faces[3 * f + 0], i1 = faces[3 * f + 1], i2 = faces[3 * f + 2];
    {
        float v0x = Vr[3 * i0], v0y = Vr[3 * i0 + 1], v0z = Vr[3 * i0 + 2];
        float v1x = Vr[3 * i1], v1y = Vr[3 * i1 + 1], v1z = Vr[3 * i1 + 2];
        float v2x = Vr[3 * i2], v2y = Vr[3 * i2 + 1], v2z = Vr[3 * i2 + 2];
        float ax = v1x - v0x, ay = v1y - v0y, az = v1z - v0z;
        float bx = v2x - v0x, by = v2y - v0y, bz = v2z - v0z;
        float nx = ay * bz - az * by, ny = az * bx - ax * bz, nz = ax * by - ay * bx;
        atomAddF(&vn_rec[3 * i0], nx); atomAddF(&vn_rec[3 * i0 + 1], ny); atomAddF(&vn_rec[3 * i0 + 2], nz);
        atomAddF(&vn_rec[3 * i1], nx); atomAddF(&vn_rec[3 * i1 + 1], ny); atomAddF(&vn_rec[3 * i1 + 2], nz);
        atomAddF(&vn_rec[3 * i2], nx); atomAddF(&vn_rec[3 * i2 + 1], ny); atomAddF(&vn_rec[3 * i2 + 2], nz);
    }
    {
        float v0x = Vg[3 * i0], v0y = Vg[3 * i0 + 1], v0z = Vg[3 * i0 + 2];
        float v1x = Vg[3 * i1], v1y = Vg[3 * i1 + 1], v1z = Vg[3 * i1 + 2];
        float v2x = Vg[3 * i2], v2y = Vg[3 * i2 + 1], v2z = Vg[3 * i2 + 2];
        float ax = v1x - v0x, ay = v1y - v0y, az = v1z - v0z;
        float bx = v2x - v0x, by = v2y - v0y, bz = v2z - v0z;
        float nx = ay * bz - az * by, ny = az * bx - ax * bz, nz = ax * by - ay * bx;
        atomAddF(&vn_gt[3 * i0], nx); atomAddF(&vn_gt[3 * i0 + 1], ny); atomAddF(&vn_gt[3 * i0 + 2], nz);
        atomAddF(&vn_gt[3 * i1], nx); atomAddF(&vn_gt[3 * i1 + 1], ny); atomAddF(&vn_gt[3 * i1 + 2], nz);
        atomAddF(&vn_gt[3 * i2], nx); atomAddF(&vn_gt[3 * i2 + 1], ny); atomAddF(&vn_gt[3 * i2 + 2], nz);
    }
}

__global__ void __launch_bounds__(256) spmm_kernel(
    const float* __restrict__ Vr, const float* __restrict__ Vg,
    const int* __restrict__ rows, const int* __restrict__ cols,
    const float* __restrict__ vals,
    float* __restrict__ dl_rec, float* __restrict__ dl_gt, int nnz)
{
    int i = blockIdx.x * blockDim.x + threadIdx.x;
    if (i >= nnz) return;
    int r = rows[i], c = cols[i];
    float v = vals[i];
    atomAddF(&dl_rec[3 * r], v * Vr[3 * c]);
    atomAddF(&dl_rec[3 * r + 1], v * Vr[3 * c + 1]);
    atomAddF(&dl_rec[3 * r + 2], v * Vr[3 * c + 2]);
    atomAddF(&dl_gt[3 * r], v * Vg[3 * c]);
    atomAddF(&dl_gt[3 * r + 1], v * Vg[3 * c + 1]);
    atomAddF(&dl_gt[3 * r + 2], v * Vg[3 * c + 2]);
}

__global__ void __launch_bounds__(256) reduce_kernel(
    const float* __restrict__ Vr, const float* __restrict__ Vg,
    const float* __restrict__ vn_rec, const float* __restrict__ vn_gt,
    const float* __restrict__ dl_rec, const float* __restrict__ dl_gt,
    float* __restrict__ accum, int N)
{
    int i = blockIdx.x * blockDim.x + threadIdx.x;
    float l1 = 0.0f, ln = 0.0f, ll = 0.0f, nonfin = 0.0f;
    if (i < N) {
        float rx = Vr[3 * i], ry = Vr[3 * i + 1], rz = Vr[3 * i + 2];
        float gx = Vg[3 * i], gy = Vg[3 * i + 1], gz = Vg[3 * i + 2];
        l1 = fabsf(rx - gx) + fabsf(ry - gy) + fabsf(rz - gz);
        float ax = vn_rec[3 * i], ay = vn_rec[3 * i + 1], az = vn_rec[3 * i + 2];
        float bx = vn_gt[3 * i],  by = vn_gt[3 * i + 1],  bz = vn_gt[3 * i + 2];
        float na = sqrtf(ax * ax + ay * ay + az * az);
        float nb = sqrtf(bx * bx + by * by + bz * bz);
        float ia = 1.0f / fmaxf(na, NORM_EPS_F);
        float ib = 1.0f / fmaxf(nb, NORM_EPS_F);
        ax *= ia; ay *= ia; az *= ia; bx *= ib; by *= ib; bz *= ib;
        float dot = ax * bx + ay * by + az * bz;
        float nna = sqrtf(ax * ax + ay * ay + az * az);
        float nnb = sqrtf(bx * bx + by * by + bz * bz);
        float cosn = dot / (fmaxf(nna, COS_EPS_F) * fmaxf(nnb, COS_EPS_F));
        if (isnan(cosn)) cosn = 1.0f;
        ln = 1.0f - cosn;
        float px = dl_rec[3 * i], py = dl_rec[3 * i + 1], pz = dl_rec[3 * i + 2];
        float qx = dl_gt[3 * i],  qy = dl_gt[3 * i + 1],  qz = dl_gt[3 * i + 2];
        bool fin = isfinite(px) && isfinite(py) && isfinite(pz) &&
                   isfinite(qx) && isfinite(qy) && isfinite(qz);
        nonfin = fin ? 0.0f : 1.0f;
        float dotl = px * qx + py * qy + pz * qz;
        float npn = sqrtf(px * px + py * py + pz * pz);
        float nqn = sqrtf(qx * qx + qy * qy + qz * qz);
        float cosl = dotl / (fmaxf(npn, COS_EPS_F) * fmaxf(nqn, COS_EPS_F));
        if (isnan(cosl)) cosl = 1.0f;
        ll = 1.0f - cosl;
    }
    float a[1] = {l1};  blockReduceAtomicN<1>(a, &accum[0]);
    float b[1] = {ln};  blockReduceAtomicN<1>(b, &accum[1]);
    float c2[2] = {ll, nonfin}; blockReduceAtomicN<2>(c2, &accum[2]);
}

// ======================= launch =======================

extern "C" void kernel_launch(void* const* d_in, const int* in_sizes, int n_in,
                              void* d_out, int out_size, void* d_ws, size_t ws_size,
                              hipStream_t stream)
{
    const float* Vr    = (const float*)d_in[0];
    const float* Vg    = (const float*)d_in[1];
    const int*   faces = (const int*)d_in[2];
    const int*   Lr    = (const int*)d_in[3];
    const int*   Lc    = (const int*)d_in[4];
    const float* Lv    = (const float*)d_in[5];

    const int N   = in_sizes[0] / 3;
    const int F   = in_sizes[2] / 3;
    const int NNZ = in_sizes[3];
    const int NB  = (N + BK - 1) >> BKSH;

    float* ws = (float*)d_ws;
    const int B = 256;

    // ---- adaptive plan (pure function of sizes -> identical every call) ----
    const long long baseW  = 4 + NBGMAX;           // accum(4) + cnt(NBGMAX)
    const long long vpackW = 8LL * N;              // packed V, 32B/vertex
    const long long fnW    = 8LL * F;              // packed face normals, 32B/face
    const long long totW   = (long long)(ws_size / 4);

    const int capF = 3 * F / (NB > 0 ? NB : 1) + 1 + 640;
    const int capL = NNZ / (NB > 0 ? NB : 1) + 1 + 640;

    long long availA = totW - baseW - vpackW - fnW;    // tier A record room
    long long availB = totW - baseW - vpackW;          // tier B record room
    bool tierA = availA >= (long long)capF * 64;
    long long availF = tierA ? availA : availB;

    int NBG_F = (int)(availF / capF);
    int NBG_L = (int)(availB / (2LL * capL));          // int2 = 2 words
    if (NBG_F > NB) NBG_F = NB;
    if (NBG_L > NB) NBG_L = NB;
    if (NBG_F > NBGMAX) NBG_F = NBGMAX;
    if (NBG_L > NBGMAX) NBG_L = NBGMAX;

    bool fast = (N <= (1 << 20)) && (F <= (1 << 22)) &&
                NBG_F >= 32 && NBG_L >= 32;

    if (fast) {
        float*    accum = ws;
        int*      cnt   = (int*)(ws + 4);
        float4*   Vp    = (float4*)(ws + baseW);
        float4*   FN    = (float4*)(ws + baseW + vpackW);
        unsigned* recF  = (unsigned*)(ws + baseW + vpackW + (tierA ? fnW : 0));
        int2*     recL  = (int2*)(ws + baseW + vpackW);   // reuses FN+recF region

        hipMemsetAsync(accum, 0, 4 * sizeof(float), stream);

        pack_l1_kernel<<<dim3((N + B - 1) / B), dim3(B), 0, stream>>>(Vr, Vg, Vp, accum, N);
        if (tierA) {
            int half = (F + 1) >> 1;
            fn_kernel<<<dim3((half + B - 1) / B), dim3(B), 0, stream>>>(Vp, faces, FN, F);
        }

        const int CHF = 4096, CHL = 8192;
        int passF = (NB + NBG_F - 1) / NBG_F;
        for (int p = 0; p < passF; ++p) {
            int b0 = p * NBG_F;
            int bcnt = NB - b0 < NBG_F ? NB - b0 : NBG_F;
            hipMemsetAsync(cnt, 0, (size_t)bcnt * sizeof(int), stream);
            bucket_faces_kernel<<<dim3((F + CHF - 1) / CHF), dim3(B), 0, stream>>>(
                faces, cnt, recF, capF, F, b0, bcnt, CHF);
            accum_normals_kernel<<<dim3(bcnt), dim3(B), 0, stream>>>(
                Vp, FN, faces, cnt, recF, capF, accum, N, b0, tierA ? 1 : 0);
        }
        int passL = (NB + NBG_L - 1) / NBG_L;
        for (int p = 0; p < passL; ++p) {
            int b0 = p * NBG_L;
            int bcnt = NB - b0 < NBG_L ? NB - b0 : NBG_L;
            hipMemsetAsync(cnt, 0, (size_t)bcnt * sizeof(int), stream);
            bucket_L_kernel<<<dim3((NNZ + CHL - 1) / CHL), dim3(B), 0, stream>>>(
                Lr, Lc, Lv, cnt, recL, capL, NNZ, b0, bcnt, CHL);
            accum_lap_kernel<<<dim3(bcnt), dim3(B), 0, stream>>>(
                Vp, cnt, recL, capL, accum, N, b0);
        }
        finalize_kernel<<<dim3(1), dim3(1), 0, stream>>>(accum, (float*)d_out, N);
    } else {
        // ---- fallback: atomic scatter path ----
        float* vn_rec = ws;
        float* vn_gt  = ws + (size_t)3 * N;
        float* dl_rec = ws + (size_t)6 * N;
        float* dl_gt  = ws + (size_t)9 * N;
        float* accum  = ws + (size_t)12 * N;
        hipMemsetAsync(d_ws, 0, ((size_t)12 * N + 4) * sizeof(float), stream);
        face_normals_kernel<<<dim3((F + B - 1) / B), dim3(B), 0, stream>>>(Vr, Vg, faces, vn_rec, vn_gt, F);
        spmm_kernel<<<dim3((NNZ + B - 1) / B), dim3(B), 0, stream>>>(Vr, Vg, Lr, Lc, Lv, dl_rec, dl_gt, NNZ);
        reduce_kernel<<<dim3((N + B - 1) / B), dim3(B), 0, stream>>>(Vr, Vg, vn_rec, vn_gt, dl_rec, dl_gt, accum, N);
        finalize_kernel<<<dim3(1), dim3(1), 0, stream>>>(accum, (float*)d_out, N);
    }
}

// Round 5
// 1097.528 us; speedup vs baseline: 1.0439x; 1.0439x over previous
//
#include <hip/hip_runtime.h>
#include <hip/hip_bf16.h>

#define NORM_EPS_F 1e-6f
#define COS_EPS_F  1e-8f
#define BK   512       // vertices per fine bucket
#define BKSH 9
#define NBGMAX 2048    // max fine buckets per pass
#define CHF1 2048      // faces per bucket_F1 block
#define CHL1 4096      // nnz per bucket_L1 block
#define K2   32        // blocks per coarse bucket in stage 2

__device__ __forceinline__ void atomAddF(float* p, float v) {
    unsafeAtomicAdd(p, v);   // hardware global_atomic_add_f32
}

template<int NV>
__device__ __forceinline__ void blockReduceAtomicN(float (&v)[NV], float* dst) {
    #pragma unroll
    for (int off = 32; off > 0; off >>= 1) {
        #pragma unroll
        for (int k = 0; k < NV; ++k) v[k] += __shfl_down(v[k], off, 64);
    }
    __shared__ float red[4][NV];
    int wave = threadIdx.x >> 6, lane = threadIdx.x & 63;
    if (lane == 0) {
        #pragma unroll
        for (int k = 0; k < NV; ++k) red[wave][k] = v[k];
    }
    __syncthreads();
    if (threadIdx.x == 0) {
        float s[NV];
        #pragma unroll
        for (int k = 0; k < NV; ++k) s[k] = 0.f;
        for (int w = 0; w < 4; ++w)
            #pragma unroll
            for (int k = 0; k < NV; ++k) s[k] += red[w][k];
        #pragma unroll
        for (int k = 0; k < NV; ++k) atomAddF(&dst[k], s[k]);
    }
}

// ======================= FAST PATH =======================

__global__ void __launch_bounds__(256) pack_l1_kernel(
    const float* __restrict__ Vr, const float* __restrict__ Vg,
    float4* __restrict__ Vp, float* __restrict__ accum, int N)
{
    int i = blockIdx.x * blockDim.x + threadIdx.x;
    float l1[1] = {0.f};
    if (i < N) {
        float rx = Vr[3 * i], ry = Vr[3 * i + 1], rz = Vr[3 * i + 2];
        float gx = Vg[3 * i], gy = Vg[3 * i + 1], gz = Vg[3 * i + 2];
        Vp[2 * i]     = make_float4(rx, ry, rz, 0.f);
        Vp[2 * i + 1] = make_float4(gx, gy, gz, 0.f);
        l1[0] = fabsf(rx - gx) + fabsf(ry - gy) + fabsf(rz - gz);
    }
    blockReduceAtomicN<1>(l1, &accum[0]);
}

// Face normals (both meshes) -> packed {nr, ng} float4 pairs. 2 faces/thread.
__global__ void __launch_bounds__(256) fn_kernel(
    const float4* __restrict__ Vp, const int* __restrict__ faces,
    float4* __restrict__ FN, int F)
{
    int half = (F + 1) >> 1;
    int t = blockIdx.x * blockDim.x + threadIdx.x;
    if (t >= half) return;
    int fi[2] = {t, t + half};
    int n = (fi[1] < F) ? 2 : 1;
    int idx[2][3];
    #pragma unroll
    for (int k = 0; k < 2; ++k) if (k < n) {
        idx[k][0] = faces[3 * fi[k]];
        idx[k][1] = faces[3 * fi[k] + 1];
        idx[k][2] = faces[3 * fi[k] + 2];
    }
    float4 r0[2], r1[2], r2[2], g0[2], g1[2], g2[2];
    #pragma unroll
    for (int k = 0; k < 2; ++k) if (k < n) {
        r0[k] = Vp[2 * idx[k][0]]; g0[k] = Vp[2 * idx[k][0] + 1];
        r1[k] = Vp[2 * idx[k][1]]; g1[k] = Vp[2 * idx[k][1] + 1];
        r2[k] = Vp[2 * idx[k][2]]; g2[k] = Vp[2 * idx[k][2] + 1];
    }
    #pragma unroll
    for (int k = 0; k < 2; ++k) if (k < n) {
        float ax = r1[k].x - r0[k].x, ay = r1[k].y - r0[k].y, az = r1[k].z - r0[k].z;
        float bx = r2[k].x - r0[k].x, by = r2[k].y - r0[k].y, bz = r2[k].z - r0[k].z;
        FN[2 * fi[k]] = make_float4(ay * bz - az * by, az * bx - ax * bz, ax * by - ay * bx, 0.f);
        ax = g1[k].x - g0[k].x; ay = g1[k].y - g0[k].y; az = g1[k].z - g0[k].z;
        bx = g2[k].x - g0[k].x; by = g2[k].y - g0[k].y; bz = g2[k].z - g0[k].z;
        FN[2 * fi[k] + 1] = make_float4(ay * bz - az * by, az * bx - ax * bz, ax * by - ay * bx, 0.f);
    }
}

// ---- Stage 1 (coarse, 64 buckets of 32 fine each): line-granular runs ----

__global__ void __launch_bounds__(256) bucket_F1(
    const int* __restrict__ faces, int* __restrict__ cntC,
    unsigned* __restrict__ recA, unsigned char* __restrict__ recC,
    int capC, int F, int b0, int bcnt, int chunk)
{
    __shared__ int hist[64];
    int f0 = blockIdx.x * chunk, f1 = min(f0 + chunk, F);
    if (threadIdx.x < 64) hist[threadIdx.x] = 0;
    __syncthreads();
    for (int f = f0 + threadIdx.x; f < f1; f += 256) {
        #pragma unroll
        for (int c = 0; c < 3; ++c) {
            unsigned fb = ((unsigned)faces[3 * f + c] >> BKSH) - (unsigned)b0;
            if (fb < (unsigned)bcnt) atomicAdd(&hist[fb >> 5], 1);
        }
    }
    __syncthreads();
    if (threadIdx.x < 64) {
        int h = hist[threadIdx.x];
        if (h) hist[threadIdx.x] = atomicAdd(&cntC[threadIdx.x], h);
    }
    __syncthreads();
    for (int f = f0 + threadIdx.x; f < f1; f += 256) {
        #pragma unroll
        for (int c = 0; c < 3; ++c) {
            int v = faces[3 * f + c];
            unsigned fb = ((unsigned)v >> BKSH) - (unsigned)b0;
            if (fb < (unsigned)bcnt) {
                int pos = atomicAdd(&hist[fb >> 5], 1);
                if (pos < capC) {
                    size_t idx = (size_t)(fb >> 5) * capC + pos;
                    recA[idx] = ((unsigned)f << BKSH) | ((unsigned)v & (BK - 1));
                    recC[idx] = (unsigned char)(fb & 31);
                }
            }
        }
    }
}

__global__ void __launch_bounds__(256) bucket_L1(
    const int* __restrict__ rows, const int* __restrict__ cols,
    const float* __restrict__ vals, int* __restrict__ cntC,
    int2* __restrict__ recA, unsigned char* __restrict__ recC,
    int capC, int nnz, int b0, int bcnt, int chunk)
{
    __shared__ int hist[64];
    int i0 = blockIdx.x * chunk, i1 = min(i0 + chunk, nnz);
    if (threadIdx.x < 64) hist[threadIdx.x] = 0;
    __syncthreads();
    for (int i = i0 + threadIdx.x; i < i1; i += 256) {
        unsigned fb = ((unsigned)rows[i] >> BKSH) - (unsigned)b0;
        if (fb < (unsigned)bcnt) atomicAdd(&hist[fb >> 5], 1);
    }
    __syncthreads();
    if (threadIdx.x < 64) {
        int h = hist[threadIdx.x];
        if (h) hist[threadIdx.x] = atomicAdd(&cntC[threadIdx.x], h);
    }
    __syncthreads();
    for (int i = i0 + threadIdx.x; i < i1; i += 256) {
        int r = rows[i];
        unsigned fb = ((unsigned)r >> BKSH) - (unsigned)b0;
        if (fb < (unsigned)bcnt) {
            int pos = atomicAdd(&hist[fb >> 5], 1);
            if (pos < capC) {
                size_t idx = (size_t)(fb >> 5) * capC + pos;
                recA[idx] = make_int2(
                    (int)(((unsigned)cols[i] << BKSH) | ((unsigned)r & (BK - 1))),
                    __float_as_int(vals[i]));
                recC[idx] = (unsigned char)(fb & 31);
            }
        }
    }
}

// ---- Stage 2 (fine, within coarse; scattered writes are L2-resident) ----

__global__ void __launch_bounds__(256) bucket_F2(
    const int* __restrict__ cntC, const unsigned* __restrict__ recA,
    const unsigned char* __restrict__ recC, int capC,
    int* __restrict__ cntFine, unsigned* __restrict__ fine, int capF)
{
    __shared__ int hist[32];
    int c = blockIdx.x;
    int K = gridDim.y, k = blockIdx.y;
    int ch = (capC + K - 1) / K;
    int n = min(cntC[c], capC);
    int i0 = k * ch, i1 = min(i0 + ch, n);
    if (threadIdx.x < 32) hist[threadIdx.x] = 0;
    __syncthreads();
    const size_t base = (size_t)c * capC;
    for (int i = i0 + threadIdx.x; i < i1; i += 256)
        atomicAdd(&hist[recC[base + i]], 1);
    __syncthreads();
    if (threadIdx.x < 32) {
        int h = hist[threadIdx.x];
        if (h) hist[threadIdx.x] = atomicAdd(&cntFine[(c << 5) + threadIdx.x], h);
    }
    __syncthreads();
    for (int i = i0 + threadIdx.x; i < i1; i += 256) {
        int fic = recC[base + i];
        int pos = atomicAdd(&hist[fic], 1);
        if (pos < capF)
            fine[(size_t)((c << 5) + fic) * capF + pos] = recA[base + i];
    }
}

__global__ void __launch_bounds__(256) bucket_L2(
    const int* __restrict__ cntC, const int2* __restrict__ recA,
    const unsigned char* __restrict__ recC, int capC,
    int* __restrict__ cntFine, int2* __restrict__ fine, int capL)
{
    __shared__ int hist[32];
    int c = blockIdx.x;
    int K = gridDim.y, k = blockIdx.y;
    int ch = (capC + K - 1) / K;
    int n = min(cntC[c], capC);
    int i0 = k * ch, i1 = min(i0 + ch, n);
    if (threadIdx.x < 32) hist[threadIdx.x] = 0;
    __syncthreads();
    const size_t base = (size_t)c * capC;
    for (int i = i0 + threadIdx.x; i < i1; i += 256)
        atomicAdd(&hist[recC[base + i]], 1);
    __syncthreads();
    if (threadIdx.x < 32) {
        int h = hist[threadIdx.x];
        if (h) hist[threadIdx.x] = atomicAdd(&cntFine[(c << 5) + threadIdx.x], h);
    }
    __syncthreads();
    for (int i = i0 + threadIdx.x; i < i1; i += 256) {
        int fic = recC[base + i];
        int pos = atomicAdd(&hist[fic], 1);
        if (pos < capL)
            fine[(size_t)((c << 5) + fic) * capL + pos] = recA[base + i];
    }
}

// ---- Accumulate + loss (unchanged from round 4) ----

__global__ void __launch_bounds__(256) accum_normals_kernel(
    const float4* __restrict__ Vp, const float4* __restrict__ FN,
    const int* __restrict__ faces,
    const int* __restrict__ cnt, const unsigned* __restrict__ recF, int capF,
    float* __restrict__ accum, int N, int b0, int use_fn)
{
    __shared__ float vnr[3 * BK];
    __shared__ float vng[3 * BK];
    int g = blockIdx.x;
    for (int i = threadIdx.x; i < 3 * BK; i += blockDim.x) { vnr[i] = 0.f; vng[i] = 0.f; }
    __syncthreads();

    const unsigned* rec = recF + (size_t)g * capF;
    int n = min(cnt[g], capF);
    int i = threadIdx.x;
    if (use_fn) {
        for (; i + 768 < n; i += 1024) {
            unsigned rc[4];
            rc[0] = rec[i]; rc[1] = rec[i + 256]; rc[2] = rec[i + 512]; rc[3] = rec[i + 768];
            float4 nr[4], ng[4];
            #pragma unroll
            for (int k = 0; k < 4; ++k) {
                int f = rc[k] >> BKSH;
                nr[k] = FN[2 * f];
                ng[k] = FN[2 * f + 1];
            }
            #pragma unroll
            for (int k = 0; k < 4; ++k) {
                int lv = rc[k] & (BK - 1);
                atomicAdd(&vnr[3 * lv + 0], nr[k].x);
                atomicAdd(&vnr[3 * lv + 1], nr[k].y);
                atomicAdd(&vnr[3 * lv + 2], nr[k].z);
                atomicAdd(&vng[3 * lv + 0], ng[k].x);
                atomicAdd(&vng[3 * lv + 1], ng[k].y);
                atomicAdd(&vng[3 * lv + 2], ng[k].z);
            }
        }
    }
    for (; i < n; i += 256) {
        unsigned rc = rec[i];
        int lv = rc & (BK - 1);
        int f  = rc >> BKSH;
        float4 nr, ng;
        if (use_fn) {
            nr = FN[2 * f];
            ng = FN[2 * f + 1];
        } else {
            int i0 = faces[3 * f], i1 = faces[3 * f + 1], i2 = faces[3 * f + 2];
            float4 r0 = Vp[2 * i0], r1 = Vp[2 * i1], r2 = Vp[2 * i2];
            float4 g0 = Vp[2 * i0 + 1], g1 = Vp[2 * i1 + 1], g2 = Vp[2 * i2 + 1];
            float ax = r1.x - r0.x, ay = r1.y - r0.y, az = r1.z - r0.z;
            float bx = r2.x - r0.x, by = r2.y - r0.y, bz = r2.z - r0.z;
            nr = make_float4(ay * bz - az * by, az * bx - ax * bz, ax * by - ay * bx, 0.f);
            ax = g1.x - g0.x; ay = g1.y - g0.y; az = g1.z - g0.z;
            bx = g2.x - g0.x; by = g2.y - g0.y; bz = g2.z - g0.z;
            ng = make_float4(ay * bz - az * by, az * bx - ax * bz, ax * by - ay * bx, 0.f);
        }
        atomicAdd(&vnr[3 * lv + 0], nr.x);
        atomicAdd(&vnr[3 * lv + 1], nr.y);
        atomicAdd(&vnr[3 * lv + 2], nr.z);
        atomicAdd(&vng[3 * lv + 0], ng.x);
        atomicAdd(&vng[3 * lv + 1], ng.y);
        atomicAdd(&vng[3 * lv + 2], ng.z);
    }
    __syncthreads();

    float ln[1] = {0.f};
    for (int lv = threadIdx.x; lv < BK; lv += blockDim.x) {
        int gv = ((b0 + g) << BKSH) + lv;
        if (gv < N) {
            float ax = vnr[3 * lv], ay = vnr[3 * lv + 1], az = vnr[3 * lv + 2];
            float bx = vng[3 * lv], by = vng[3 * lv + 1], bz = vng[3 * lv + 2];
            float na = sqrtf(ax * ax + ay * ay + az * az);
            float nb = sqrtf(bx * bx + by * by + bz * bz);
            float ia = 1.0f / fmaxf(na, NORM_EPS_F);
            float ib = 1.0f / fmaxf(nb, NORM_EPS_F);
            ax *= ia; ay *= ia; az *= ia;
            bx *= ib; by *= ib; bz *= ib;
            float dot = ax * bx + ay * by + az * bz;
            float nna = sqrtf(ax * ax + ay * ay + az * az);
            float nnb = sqrtf(bx * bx + by * by + bz * bz);
            float cosn = dot / (fmaxf(nna, COS_EPS_F) * fmaxf(nnb, COS_EPS_F));
            if (isnan(cosn)) cosn = 1.0f;
            ln[0] += 1.0f - cosn;
        }
    }
    blockReduceAtomicN<1>(ln, &accum[1]);
}

__global__ void __launch_bounds__(256) accum_lap_kernel(
    const float4* __restrict__ Vp,
    const int* __restrict__ cnt, const int2* __restrict__ recL, int capL,
    float* __restrict__ accum, int N, int b0)
{
    __shared__ float dlr[3 * BK];
    __shared__ float dlg[3 * BK];
    int g = blockIdx.x;
    for (int i = threadIdx.x; i < 3 * BK; i += blockDim.x) { dlr[i] = 0.f; dlg[i] = 0.f; }
    __syncthreads();

    const int2* rec = recL + (size_t)g * capL;
    int n = min(cnt[g], capL);
    int i = threadIdx.x;
    for (; i + 768 < n; i += 1024) {
        int2 rc[4];
        rc[0] = rec[i]; rc[1] = rec[i + 256]; rc[2] = rec[i + 512]; rc[3] = rec[i + 768];
        float4 pr[4], pg[4];
        #pragma unroll
        for (int k = 0; k < 4; ++k) {
            int col = (unsigned)rc[k].x >> BKSH;
            pr[k] = Vp[2 * col];
            pg[k] = Vp[2 * col + 1];
        }
        #pragma unroll
        for (int k = 0; k < 4; ++k) {
            int lv = (unsigned)rc[k].x & (BK - 1);
            float v = __int_as_float(rc[k].y);
            atomicAdd(&dlr[3 * lv + 0], v * pr[k].x);
            atomicAdd(&dlr[3 * lv + 1], v * pr[k].y);
            atomicAdd(&dlr[3 * lv + 2], v * pr[k].z);
            atomicAdd(&dlg[3 * lv + 0], v * pg[k].x);
            atomicAdd(&dlg[3 * lv + 1], v * pg[k].y);
            atomicAdd(&dlg[3 * lv + 2], v * pg[k].z);
        }
    }
    for (; i < n; i += 256) {
        int2 rc = rec[i];
        unsigned u = (unsigned)rc.x;
        int lv  = u & (BK - 1);
        int col = u >> BKSH;
        float v = __int_as_float(rc.y);
        float4 pr = Vp[2 * col];
        float4 pg = Vp[2 * col + 1];
        atomicAdd(&dlr[3 * lv + 0], v * pr.x);
        atomicAdd(&dlr[3 * lv + 1], v * pr.y);
        atomicAdd(&dlr[3 * lv + 2], v * pr.z);
        atomicAdd(&dlg[3 * lv + 0], v * pg.x);
        atomicAdd(&dlg[3 * lv + 1], v * pg.y);
        atomicAdd(&dlg[3 * lv + 2], v * pg.z);
    }
    __syncthreads();

    float vals2[2] = {0.f, 0.f};
    for (int lv = threadIdx.x; lv < BK; lv += blockDim.x) {
        int gv = ((b0 + g) << BKSH) + lv;
        if (gv < N) {
            float px = dlr[3 * lv], py = dlr[3 * lv + 1], pz = dlr[3 * lv + 2];
            float qx = dlg[3 * lv], qy = dlg[3 * lv + 1], qz = dlg[3 * lv + 2];
            bool fin = isfinite(px) && isfinite(py) && isfinite(pz) &&
                       isfinite(qx) && isfinite(qy) && isfinite(qz);
            vals2[1] += fin ? 0.f : 1.f;
            float dotl = px * qx + py * qy + pz * qz;
            float npn = sqrtf(px * px + py * py + pz * pz);
            float nqn = sqrtf(qx * qx + qy * qy + qz * qz);
            float cosl = dotl / (fmaxf(npn, COS_EPS_F) * fmaxf(nqn, COS_EPS_F));
            if (isnan(cosl)) cosl = 1.0f;
            vals2[0] += 1.0f - cosl;
        }
    }
    blockReduceAtomicN<2>(vals2, &accum[2]);
}

__global__ void finalize_kernel(const float* __restrict__ accum,
                                float* __restrict__ out, int N)
{
    float invN = 1.0f / (float)N;
    float l1 = accum[0] * invN * (1.0f / 3.0f);
    float ln = accum[1] * invN;
    float ll = (accum[3] > 0.0f) ? 0.0f : accum[2] * invN;
    out[0] = 1.0f * l1 + 1.0f * ln + 0.1f * ll;
}

// ======================= FALLBACK PATH (round-1, known correct) =======================

__global__ void __launch_bounds__(256) face_normals_kernel(
    const float* __restrict__ Vr, const float* __restrict__ Vg,
    const int* __restrict__ faces,
    float* __restrict__ vn_rec, float* __restrict__ vn_gt, int F)
{
    int f = blockIdx.x * blockDim.x + threadIdx.x;
    if (f >= F) return;
    int i0 = faces[3 * f + 0], i1 = faces[3 * f + 1], i2 = faces[3 * f + 2];
    {
        float v0x = Vr[3 * i0], v0y = Vr[3 * i0 + 1], v0z = Vr[3 * i0 + 2];
        float v1x = Vr[3 * i1], v1y = Vr[3 * i1 + 1], v1z = Vr[3 * i1 + 2];
        float v2x = Vr[3 * i2], v2y = Vr[3 * i2 + 1], v2z = Vr[3 * i2 + 2];
        float ax = v1x - v0x, ay = v1y - v0y, az = v1z - v0z;
        float bx = v2x - v0x, by = v2y - v0y, bz = v2z - v0z;
        float nx = ay * bz - az * by, ny = az * bx - ax * bz, nz = ax * by - ay * bx;
        atomAddF(&vn_rec[3 * i0], nx); atomAddF(&vn_rec[3 * i0 + 1], ny); atomAddF(&vn_rec[3 * i0 + 2], nz);
        atomAddF(&vn_rec[3 * i1], nx); atomAddF(&vn_rec[3 * i1 + 1], ny); atomAddF(&vn_rec[3 * i1 + 2], nz);
        atomAddF(&vn_rec[3 * i2], nx); atomAddF(&vn_rec[3 * i2 + 1], ny); atomAddF(&vn_rec[3 * i2 + 2], nz);
    }
    {
        float v0x = Vg[3 * i0], v0y = Vg[3 * i0 + 1], v0z = Vg[3 * i0 + 2];
        float v1x = Vg[3 * i1], v1y = Vg[3 * i1 + 1], v1z = Vg[3 * i1 + 2];
        float v2x = Vg[3 * i2], v2y = Vg[3 * i2 + 1], v2z = Vg[3 * i2 + 2];
        float ax = v1x - v0x, ay = v1y - v0y, az = v1z - v0z;
        float bx = v2x - v0x, by = v2y - v0y, bz = v2z - v0z;
        float nx = ay * bz - az * by, ny = az * bx - ax * bz, nz = ax * by - ay * bx;
        atomAddF(&vn_gt[3 * i0], nx); atomAddF(&vn_gt[3 * i0 + 1], ny); atomAddF(&vn_gt[3 * i0 + 2], nz);
        atomAddF(&vn_gt[3 * i1], nx); atomAddF(&vn_gt[3 * i1 + 1], ny); atomAddF(&vn_gt[3 * i1 + 2], nz);
        atomAddF(&vn_gt[3 * i2], nx); atomAddF(&vn_gt[3 * i2 + 1], ny); atomAddF(&vn_gt[3 * i2 + 2], nz);
    }
}

__global__ void __launch_bounds__(256) spmm_kernel(
    const float* __restrict__ Vr, const float* __restrict__ Vg,
    const int* __restrict__ rows, const int* __restrict__ cols,
    const float* __restrict__ vals,
    float* __restrict__ dl_rec, float* __restrict__ dl_gt, int nnz)
{
    int i = blockIdx.x * blockDim.x + threadIdx.x;
    if (i >= nnz) return;
    int r = rows[i], c = cols[i];
    float v = vals[i];
    atomAddF(&dl_rec[3 * r], v * Vr[3 * c]);
    atomAddF(&dl_rec[3 * r + 1], v * Vr[3 * c + 1]);
    atomAddF(&dl_rec[3 * r + 2], v * Vr[3 * c + 2]);
    atomAddF(&dl_gt[3 * r], v * Vg[3 * c]);
    atomAddF(&dl_gt[3 * r + 1], v * Vg[3 * c + 1]);
    atomAddF(&dl_gt[3 * r + 2], v * Vg[3 * c + 2]);
}

__global__ void __launch_bounds__(256) reduce_kernel(
    const float* __restrict__ Vr, const float* __restrict__ Vg,
    const float* __restrict__ vn_rec, const float* __restrict__ vn_gt,
    const float* __restrict__ dl_rec, const float* __restrict__ dl_gt,
    float* __restrict__ accum, int N)
{
    int i = blockIdx.x * blockDim.x + threadIdx.x;
    float l1 = 0.0f, ln = 0.0f, ll = 0.0f, nonfin = 0.0f;
    if (i < N) {
        float rx = Vr[3 * i], ry = Vr[3 * i + 1], rz = Vr[3 * i + 2];
        float gx = Vg[3 * i], gy = Vg[3 * i + 1], gz = Vg[3 * i + 2];
        l1 = fabsf(rx - gx) + fabsf(ry - gy) + fabsf(rz - gz);
        float ax = vn_rec[3 * i], ay = vn_rec[3 * i + 1], az = vn_rec[3 * i + 2];
        float bx = vn_gt[3 * i],  by = vn_gt[3 * i + 1],  bz = vn_gt[3 * i + 2];
        float na = sqrtf(ax * ax + ay * ay + az * az);
        float nb = sqrtf(bx * bx + by * by + bz * bz);
        float ia = 1.0f / fmaxf(na, NORM_EPS_F);
        float ib = 1.0f / fmaxf(nb, NORM_EPS_F);
        ax *= ia; ay *= ia; az *= ia; bx *= ib; by *= ib; bz *= ib;
        float dot = ax * bx + ay * by + az * bz;
        float nna = sqrtf(ax * ax + ay * ay + az * az);
        float nnb = sqrtf(bx * bx + by * by + bz * bz);
        float cosn = dot / (fmaxf(nna, COS_EPS_F) * fmaxf(nnb, COS_EPS_F));
        if (isnan(cosn)) cosn = 1.0f;
        ln = 1.0f - cosn;
        float px = dl_rec[3 * i], py = dl_rec[3 * i + 1], pz = dl_rec[3 * i + 2];
        float qx = dl_gt[3 * i],  qy = dl_gt[3 * i + 1],  qz = dl_gt[3 * i + 2];
        bool fin = isfinite(px) && isfinite(py) && isfinite(pz) &&
                   isfinite(qx) && isfinite(qy) && isfinite(qz);
        nonfin = fin ? 0.0f : 1.0f;
        float dotl = px * qx + py * qy + pz * qz;
        float npn = sqrtf(px * px + py * py + pz * pz);
        float nqn = sqrtf(qx * qx + qy * qy + qz * qz);
        float cosl = dotl / (fmaxf(npn, COS_EPS_F) * fmaxf(nqn, COS_EPS_F));
        if (isnan(cosl)) cosl = 1.0f;
        ll = 1.0f - cosl;
    }
    float a[1] = {l1};  blockReduceAtomicN<1>(a, &accum[0]);
    float b[1] = {ln};  blockReduceAtomicN<1>(b, &accum[1]);
    float c2[2] = {ll, nonfin}; blockReduceAtomicN<2>(c2, &accum[2]);
}

// ======================= launch =======================

extern "C" void kernel_launch(void* const* d_in, const int* in_sizes, int n_in,
                              void* d_out, int out_size, void* d_ws, size_t ws_size,
                              hipStream_t stream)
{
    const float* Vr    = (const float*)d_in[0];
    const float* Vg    = (const float*)d_in[1];
    const int*   faces = (const int*)d_in[2];
    const int*   Lr    = (const int*)d_in[3];
    const int*   Lc    = (const int*)d_in[4];
    const float* Lv    = (const float*)d_in[5];

    const int N   = in_sizes[0] / 3;
    const int F   = in_sizes[2] / 3;
    const int NNZ = in_sizes[3];
    const int NB  = (N + BK - 1) >> BKSH;

    float* ws = (float*)d_ws;
    const int B = 256;

    // ---- adaptive plan (pure function of sizes) ----
    const long long totW   = (long long)(ws_size / 4);
    const long long fixedW = 4 + 64 + NBGMAX;              // accum, cntC, cntFine
    const long long vpW    = 8LL * N;
    const long long arenaW = totW - fixedW - vpW;
    const long long fnW    = 8LL * F;

    const int capF = 3 * F / (NB > 0 ? NB : 1) + 1 + 640;
    const int capL = NNZ / (NB > 0 ? NB : 1) + 1 + 640;

    auto fwords = [&](int nbg) -> long long {
        long long nc = (nbg + 31) / 32, capC = 32LL * capF;
        return nc * capC + (nc * capC + 3) / 4 + (long long)nbg * capF + 4;
    };
    auto lwords = [&](int nbg) -> long long {
        long long nc = (nbg + 31) / 32, capC = 32LL * capL;
        return nc * capC * 2 + (((nc * capC + 3) / 4 + 1) & ~1LL) + (long long)nbg * capL * 2 + 4;
    };

    int NBG_F = NB < NBGMAX ? NB : NBGMAX;
    bool tierA = (arenaW - fnW) >= fwords(64);
    long long arenaF = tierA ? (arenaW - fnW) : arenaW;
    while (NBG_F > 64 && fwords(NBG_F) > arenaF) NBG_F -= 32;
    int NBG_L = NB < NBGMAX ? NB : NBGMAX;
    while (NBG_L > 64 && lwords(NBG_L) > arenaW) NBG_L -= 32;

    bool fast = (N <= (1 << 20)) && (F <= (1 << 22)) &&
                NBG_F >= 64 && NBG_L >= 64 &&
                fwords(NBG_F) <= arenaF && lwords(NBG_L) <= arenaW &&
                arenaW > 0;

    if (fast) {
        float*  accum   = ws;
        int*    cntC    = (int*)(ws + 4);
        int*    cntFine = (int*)(ws + 68);
        float4* Vp      = (float4*)(ws + fixedW);
        float*  arena   = ws + fixedW + vpW;

        // face-phase layout
        const long long NCF = (NBG_F + 31) / 32, capCF = 32LL * capF;
        float4*        FN    = (float4*)arena;
        float*         fbase = tierA ? (arena + fnW) : arena;
        unsigned*      recAF = (unsigned*)fbase;
        unsigned char* recCF = (unsigned char*)(recAF + NCF * capCF);
        unsigned*      fineF = (unsigned*)(fbase + NCF * capCF + (NCF * capCF + 3) / 4);

        // L-phase layout (reuses the whole arena; runs after face phase)
        const long long NCL = (NBG_L + 31) / 32, capCL = 32LL * capL;
        int2*          recAL = (int2*)arena;
        unsigned char* recCL = (unsigned char*)(recAL + NCL * capCL);
        const long long bytesWL = ((NCL * capCL + 3) / 4 + 1) & ~1LL;
        int2*          fineL = (int2*)(arena + NCL * capCL * 2 + bytesWL);

        hipMemsetAsync(accum, 0, 4 * sizeof(float), stream);

        pack_l1_kernel<<<dim3((N + B - 1) / B), dim3(B), 0, stream>>>(Vr, Vg, Vp, accum, N);
        if (tierA) {
            int half = (F + 1) >> 1;
            fn_kernel<<<dim3((half + B - 1) / B), dim3(B), 0, stream>>>(Vp, faces, FN, F);
        }

        int passF = (NB + NBG_F - 1) / NBG_F;
        for (int p = 0; p < passF; ++p) {
            int b0 = p * NBG_F;
            int bcnt = NB - b0 < NBG_F ? NB - b0 : NBG_F;
            int nc = (bcnt + 31) / 32;
            hipMemsetAsync(ws + 4, 0, (64 + NBGMAX) * sizeof(int), stream);
            bucket_F1<<<dim3((F + CHF1 - 1) / CHF1), dim3(B), 0, stream>>>(
                faces, cntC, recAF, recCF, (int)capCF, F, b0, bcnt, CHF1);
            bucket_F2<<<dim3(nc, K2), dim3(B), 0, stream>>>(
                cntC, recAF, recCF, (int)capCF, cntFine, fineF, capF);
            accum_normals_kernel<<<dim3(bcnt), dim3(B), 0, stream>>>(
                Vp, FN, faces, cntFine, fineF, capF, accum, N, b0, tierA ? 1 : 0);
        }

        int passL = (NB + NBG_L - 1) / NBG_L;
        for (int p = 0; p < passL; ++p) {
            int b0 = p * NBG_L;
            int bcnt = NB - b0 < NBG_L ? NB - b0 : NBG_L;
            int nc = (bcnt + 31) / 32;
            hipMemsetAsync(ws + 4, 0, (64 + NBGMAX) * sizeof(int), stream);
            bucket_L1<<<dim3((NNZ + CHL1 - 1) / CHL1), dim3(B), 0, stream>>>(
                Lr, Lc, Lv, cntC, recAL, recCL, (int)capCL, NNZ, b0, bcnt, CHL1);
            bucket_L2<<<dim3(nc, K2), dim3(B), 0, stream>>>(
                cntC, recAL, recCL, (int)capCL, cntFine, fineL, capL);
            accum_lap_kernel<<<dim3(bcnt), dim3(B), 0, stream>>>(
                Vp, cntFine, fineL, capL, accum, N, b0);
        }
        finalize_kernel<<<dim3(1), dim3(1), 0, stream>>>(accum, (float*)d_out, N);
    } else {
        float* vn_rec = ws;
        float* vn_gt  = ws + (size_t)3 * N;
        float* dl_rec = ws + (size_t)6 * N;
        float* dl_gt  = ws + (size_t)9 * N;
        float* accum  = ws + (size_t)12 * N;
        hipMemsetAsync(d_ws, 0, ((size_t)12 * N + 4) * sizeof(float), stream);
        face_normals_kernel<<<dim3((F + B - 1) / B), dim3(B), 0, stream>>>(Vr, Vg, faces, vn_rec, vn_gt, F);
        spmm_kernel<<<dim3((NNZ + B - 1) / B), dim3(B), 0, stream>>>(Vr, Vg, Lr, Lc, Lv, dl_rec, dl_gt, NNZ);
        reduce_kernel<<<dim3((N + B - 1) / B), dim3(B), 0, stream>>>(Vr, Vg, vn_rec, vn_gt, dl_rec, dl_gt, accum, N);
        finalize_kernel<<<dim3(1), dim3(1), 0, stream>>>(accum, (float*)d_out, N);
    }
}